// Round 1
// baseline (283.809 us; speedup 1.0000x reference)
//
#include <hip/hip_runtime.h>
#include <hip/hip_bf16.h>
#include <cstdint>

typedef _Float16 f16;
typedef f16 f16x8 __attribute__((ext_vector_type(8)));
typedef f16 f16x4 __attribute__((ext_vector_type(4)));
typedef float f32x4 __attribute__((ext_vector_type(4)));

#define MFMA16(a, b, c) __builtin_amdgcn_mfma_f32_16x16x32_f16((a), (b), (c), 0, 0, 0)

constexpr int Bc = 4, Sc = 2048, Dc = 1024, Hc = 16, DHc = 64;

typedef __attribute__((address_space(1))) const uint32_t gbl_u32;
typedef __attribute__((address_space(3))) uint32_t lds_u32;
__device__ __forceinline__ void gld_lds16(const void* g, void* l) {
  __builtin_amdgcn_global_load_lds((gbl_u32*)g, (lds_u32*)l, 16, 0, 0);
}

// ---------------------------------------------------------------------------
// Kernel 1: cast+transpose weights: W fp32 [K=1024][N=1024] -> Wt f16 [z][N][K]
// ---------------------------------------------------------------------------
__global__ __launch_bounds__(256) void cast_w_kernel(
    const float* __restrict__ Wq, const float* __restrict__ Wk,
    const float* __restrict__ Wv, f16* __restrict__ Wt) {
  __shared__ __align__(16) f16 T[64][66];
  const int z = blockIdx.z;
  const float* W = (z == 0) ? Wq : (z == 1) ? Wk : Wv;
  const int n0 = blockIdx.x * 64, k0 = blockIdx.y * 64;
  const int t = threadIdx.x;
#pragma unroll
  for (int p = 0; p < 4; p++) {
    int idx = t + p * 256;
    int r = idx >> 4, c = idx & 15;
    float4 v = *(const float4*)(W + (size_t)(k0 + r) * Dc + n0 + c * 4);
    T[r][c * 4 + 0] = (f16)v.x;
    T[r][c * 4 + 1] = (f16)v.y;
    T[r][c * 4 + 2] = (f16)v.z;
    T[r][c * 4 + 3] = (f16)v.w;
  }
  __syncthreads();
#pragma unroll
  for (int p = 0; p < 2; p++) {
    int idx = t + p * 256;
    int n = idx >> 3, c = idx & 7;
    f16x8 tmp;
#pragma unroll
    for (int j = 0; j < 8; j++) tmp[j] = T[c * 8 + j][n];
    *(f16x8*)(Wt + ((size_t)z * Dc + n0 + n) * Dc + k0 + c * 8) = tmp;
  }
}

// ---------------------------------------------------------------------------
// Kernel 1b: cast X fp32 -> f16.
// ---------------------------------------------------------------------------
__global__ __launch_bounds__(256) void cast_x_kernel(const float* __restrict__ X,
                                                     f16* __restrict__ X16) {
  size_t i = ((size_t)blockIdx.x * 256 + threadIdx.x) * 8;
  float4 a = *(const float4*)(X + i);
  float4 b = *(const float4*)(X + i + 4);
  f16x8 h;
  h[0] = (f16)a.x; h[1] = (f16)a.y; h[2] = (f16)a.z; h[3] = (f16)a.w;
  h[4] = (f16)b.x; h[5] = (f16)b.y; h[6] = (f16)b.z; h[7] = (f16)b.w;
  *(f16x8*)(X16 + i) = h;
}

// ---------------------------------------------------------------------------
// Kernel 2: QKV GEMM, m97-style. Q is pre-scaled by 1/8 * log2(e) so the
// flash kernel can use v_exp_f32 (exp2) directly without the per-score mul.
// ---------------------------------------------------------------------------
__global__ __launch_bounds__(256) void qkv_gemm_kernel(
    const f16* __restrict__ X16, const f16* __restrict__ Wt,
    const float* __restrict__ bq, const float* __restrict__ bk,
    const float* __restrict__ bv, f16* __restrict__ Qo, f16* __restrict__ Ko,
    f16* __restrict__ Vo) {
  const int z = blockIdx.z;
  const f16* W = Wt + (size_t)z * Dc * Dc;
  const float* bias = (z == 0) ? bq : (z == 1) ? bk : bv;

  const int n0 = blockIdx.x * 128, m0 = blockIdx.y * 128;
  __shared__ __align__(16) f16 Xs[128 * 32];
  __shared__ __align__(16) f16 Ws[128 * 32];

  const int t = threadIdx.x;
  const int wave = t >> 6, lane = t & 63;
  const int l16 = lane & 15, quad = lane >> 4;
  const int wm = (wave >> 1) * 64, wn = (wave & 1) * 64;

  f32x4 acc[4][4];
#pragma unroll
  for (int i = 0; i < 4; i++)
#pragma unroll
    for (int j = 0; j < 4; j++) acc[i][j] = (f32x4){0.f, 0.f, 0.f, 0.f};

  for (int k0 = 0; k0 < Dc; k0 += 32) {
#pragma unroll
    for (int p = 0; p < 2; p++) {
      int cb = p * 256 + wave * 64;
      int chunk = cb + lane;
      int row = chunk >> 2, c8 = (chunk & 3) * 8;
      gld_lds16(X16 + (size_t)(m0 + row) * Dc + k0 + c8, (f16*)Xs + (size_t)cb * 8);
      gld_lds16(W + (size_t)(n0 + row) * Dc + k0 + c8, (f16*)Ws + (size_t)cb * 8);
    }
    __syncthreads();

    f16x8 aF[4], bF[4];
#pragma unroll
    for (int mt = 0; mt < 4; mt++)
      aF[mt] = *(const f16x8*)(&Xs[(wm + mt * 16 + l16) * 32 + quad * 8]);
#pragma unroll
    for (int nt = 0; nt < 4; nt++)
      bF[nt] = *(const f16x8*)(&Ws[(wn + nt * 16 + l16) * 32 + quad * 8]);
#pragma unroll
    for (int mt = 0; mt < 4; mt++)
#pragma unroll
      for (int nt = 0; nt < 4; nt++)
        acc[mt][nt] = MFMA16(aF[mt], bF[nt], acc[mt][nt]);
    __syncthreads();
  }

#pragma unroll
  for (int nt = 0; nt < 4; nt++) {
    int col = n0 + wn + nt * 16 + l16;
    float bval = bias[col];
    int h = col >> 6, d = col & 63;
    if (z == 2) {
#pragma unroll
      for (int mt = 0; mt < 4; mt++) {
        int m = m0 + wm + mt * 16 + quad * 4;
        int b = m >> 11, sbase = m & 2047;
        f16x4 pk;
#pragma unroll
        for (int r = 0; r < 4; r++) pk[r] = (f16)(acc[mt][nt][r] + bval);
        *(f16x4*)(Vo + (((size_t)(b * Hc + h)) * DHc + d) * Sc + sbase) = pk;
      }
    } else {
      // z==0 (Q): fold softmax scale 1/sqrt(64)=0.125 AND log2(e) so flash
      // uses exp2 directly.  z==1 (K): 1.0.
      const float sc = (z == 0) ? 0.18033688011112042f : 1.0f;
      f16* O = (z == 0) ? Qo : Ko;
#pragma unroll
      for (int mt = 0; mt < 4; mt++) {
#pragma unroll
        for (int r = 0; r < 4; r++) {
          int m = m0 + wm + mt * 16 + quad * 4 + r;
          int b = m >> 11, s = m & 2047;
          O[(((size_t)(b * Hc + h)) * Sc + s) * DHc + d] =
              (f16)((acc[mt][nt][r] + bval) * sc);
        }
      }
    }
  }
}

// ---------------------------------------------------------------------------
// Kernel 3: flash attention — register-resident P via KEY-PERMUTED K staging.
// (See prior revision for the permutation derivation; unchanged here.)
//
// This revision is a VALU diet (rocprof: VALUBusy 56% vs MfmaUtil 24.5%):
//  - Q pre-scaled by log2(e), mask scaled by log2(e) at load -> raw
//    v_exp_f32 (exp2) per score, no per-score v_mul.
//  - row-sum l computed by 4 extra MFMAs against an all-ones B-fragment
//    (moves 32 v_add/chunk onto the 24%-busy MFMA pipe); D-layout lands l
//    at exactly the (quad*4+r) rows the epilogue stores, so the shfl
//    reduce/redistribute is gone. l also now sums the same f16-rounded P
//    used in the PV numerator (consistent normalization).
//  - staging addresses (K/V global ptrs, LDS offsets, mask ptr) hoisted out
//    of the chunk loop; per chunk only pointer increments remain.
// ---------------------------------------------------------------------------
__global__ __launch_bounds__(256) void flash_kernel(
    const f16* __restrict__ Q, const f16* __restrict__ K,
    const f16* __restrict__ Vt, const float* __restrict__ mask,
    float* __restrict__ out) {
  const int bh = blockIdx.y;
  const int b = bh >> 4, h = bh & 15;
  const int t = threadIdx.x;
  const int wave = t >> 6, lane = t & 63;
  const int l16 = lane & 15, quad = lane >> 4;
  const int qbase = blockIdx.x * 128 + wave * 32;

  __shared__ __align__(16) f16 Ks[2][4096];  // [buf][half*2048+row*32+oct*8]
  __shared__ __align__(16) f16 Vs[2][4096];  // [buf][kh*2048+dh*32+oct*8]

  const f16* Kb = K + (size_t)bh * Sc * DHc;
  const f16* Vb = Vt + (size_t)bh * DHc * Sc;

  // swizzled b128 read position (same for K and V frags)
  const int qsw8 = (quad ^ ((l16 >> 1) & 3)) * 8;

  // ---- hoisted staging state: per-lane global ptrs + wave-uniform LDS offs.
  // octet i -> half=i>>8, row=(i>>2)&63, pos q8=i&3 holds global octet
  // q8^((row>>1)&3). K rows are PERMUTED: staged row k holds global key
  // phys(k): [n1 n0 q1 q0 r1 r0] -> [n1 q1 q0 n0 r1 r0].
  const f16* kp[2];
  const f16* vp[2];
  int ldsOff[2];
#pragma unroll
  for (int p = 0; p < 2; p++) {
    int cb = p * 256 + wave * 64;  // wave-uniform octet base
    int i = cb + lane;
    int half = i >> 8, row = (i >> 2) & 63, q8 = i & 3;
    int q8g = q8 ^ ((row >> 1) & 3);
    int g = (row & 32) | ((row & 12) << 1) | ((row & 16) >> 2) | (row & 3);
    kp[p] = Kb + (size_t)g * DHc + half * 32 + q8g * 8;
    vp[p] = Vb + (size_t)row * Sc + half * 32 + q8g * 8;
    ldsOff[p] = cb * 8;
  }
  auto stage = [&](int buf) {
#pragma unroll
    for (int p = 0; p < 2; p++) {
      gld_lds16(kp[p], (f16*)Ks + buf * 4096 + ldsOff[p]);
      gld_lds16(vp[p], (f16*)Vs + buf * 4096 + ldsOff[p]);
      kp[p] += 64 * DHc;  // next chunk: 64 more key rows
      vp[p] += 64;        // next chunk: 64 more key columns
    }
  };

  // mask ptr: chunk-c addresses are mp + {0,4,32,36}, then mp += 64.
  const float* mp = mask + (size_t)b * Sc + quad * 8;

  // Q B-frags for 2 m-tiles (B[k=quad*8+j -> dh][n=l16 -> query]); pre-scaled
  // by 0.125*log2(e) in the GEMM epilogue.
  f16x8 qa[2][2];
#pragma unroll
  for (int mt = 0; mt < 2; mt++) {
    const f16* qb = Q + ((size_t)bh * Sc + qbase + mt * 16 + l16) * DHc;
    qa[mt][0] = *(const f16x8*)(qb + quad * 8);
    qa[mt][1] = *(const f16x8*)(qb + 32 + quad * 8);
  }

  // all-ones B-frag for the l row-sum MFMAs
  f16x8 ones;
#pragma unroll
  for (int j = 0; j < 8; j++) ones[j] = (f16)1.0f;

  // prologue: stage chunk 0
  stage(0);
  __syncthreads();

  f32x4 lacc[2];
  f32x4 o[2][4];
#pragma unroll
  for (int mt = 0; mt < 2; mt++) {
    lacc[mt] = (f32x4){0.f, 0.f, 0.f, 0.f};
#pragma unroll
    for (int dt = 0; dt < 4; dt++) o[mt][dt] = (f32x4){0.f, 0.f, 0.f, 0.f};
  }

  constexpr float L2E = 1.44269504088896340736f;

  for (int c = 0; c < 32; c++) {
    const int buf = c & 1;
    // mask loads FIRST (in-order vmcnt: waiting for these leaves the staging
    // issued below in flight). Address = permuted key of staged (nt,quad,r).
    float4 mv[4];
    mv[0] = *(const float4*)(mp + 0);
    mv[1] = *(const float4*)(mp + 4);
    mv[2] = *(const float4*)(mp + 32);
    mv[3] = *(const float4*)(mp + 36);
    mp += 64;
    if (c < 31) stage(buf ^ 1);

    // scale mask into exp2 domain
    f32x4 minit[4];
#pragma unroll
    for (int nt = 0; nt < 4; nt++)
      minit[nt] = (f32x4){mv[nt].x * L2E, mv[nt].y * L2E, mv[nt].z * L2E,
                          mv[nt].w * L2E};

    // K A-frags (staged/permuted rows), swizzled b128 positions
    f16x8 ka[4][2];
#pragma unroll
    for (int nt = 0; nt < 4; nt++) {
      int rb = (nt * 16 + l16) * 32 + qsw8;
      ka[nt][0] = *(const f16x8*)(&Ks[buf][rb]);
      ka[nt][1] = *(const f16x8*)(&Ks[buf][2048 + rb]);
    }

    // ---- QK both m-tiles: S^T = K*Q^T + mask (C-init), log2 domain ----
    f32x4 s0[4], s1[4];
#pragma unroll
    for (int nt = 0; nt < 4; nt++) {
      f32x4 a = minit[nt];
      a = MFMA16(ka[nt][0], qa[0][0], a);
      a = MFMA16(ka[nt][1], qa[0][1], a);
      s0[nt] = a;
      f32x4 a2 = minit[nt];
      a2 = MFMA16(ka[nt][0], qa[1][0], a2);
      a2 = MFMA16(ka[nt][1], qa[1][1], a2);
      s1[nt] = a2;
    }

    // ---- exp2 + pack: s[2blk+(j>=4)][j&3] -> A-frag element j of block blk.
    // Under the key permutation this IS the 16x16x32 A-layout. ----
    f16x8 pa[2][2];  // [mt][blk]
#pragma unroll
    for (int blk = 0; blk < 2; blk++) {
      f16x8 p0, p1;
#pragma unroll
      for (int half = 0; half < 2; half++) {
        int nt = blk * 2 + half;
#pragma unroll
        for (int r = 0; r < 4; r++) {
          p0[half * 4 + r] = (f16)__builtin_amdgcn_exp2f(s0[nt][r]);
          p1[half * 4 + r] = (f16)__builtin_amdgcn_exp2f(s1[nt][r]);
        }
      }
      pa[0][blk] = p0;
      pa[1][blk] = p1;
    }

    // ---- l row-sums on the MFMA pipe: D[q][*] = sum_k P[q][k] ----
    lacc[0] = MFMA16(pa[0][0], ones, lacc[0]);
    lacc[0] = MFMA16(pa[0][1], ones, lacc[0]);
    lacc[1] = MFMA16(pa[1][0], ones, lacc[1]);
    lacc[1] = MFMA16(pa[1][1], ones, lacc[1]);

    // ---- PV: 16x16x32, V b128 frags shared by both m-tiles (0-conflict) ----
#pragma unroll
    for (int dt = 0; dt < 4; dt++) {
      int rb = (dt * 16 + l16) * 32 + qsw8;
      f16x8 v0 = *(const f16x8*)(&Vs[buf][rb]);
      f16x8 v1 = *(const f16x8*)(&Vs[buf][2048 + rb]);
      o[0][dt] = MFMA16(pa[0][0], v0, o[0][dt]);
      o[0][dt] = MFMA16(pa[0][1], v1, o[0][dt]);
      o[1][dt] = MFMA16(pa[1][0], v0, o[1][dt]);
      o[1][dt] = MFMA16(pa[1][1], v1, o[1][dt]);
    }

    // one barrier per chunk: all waves done with buf; staging of c+1 drains.
    __syncthreads();
  }

  // ---- epilogue: lacc D-layout rows (quad*4+r) == o rows; no shuffles ----
#pragma unroll
  for (int mt = 0; mt < 2; mt++) {
    float inv[4];
#pragma unroll
    for (int r = 0; r < 4; r++) inv[r] = 1.0f / lacc[mt][r];
#pragma unroll
    for (int dt = 0; dt < 4; dt++) {
      int col = h * 64 + dt * 16 + l16;
#pragma unroll
      for (int r = 0; r < 4; r++) {
        int row = qbase + mt * 16 + quad * 4 + r;
        out[((size_t)b * Sc + row) * Dc + col] = o[mt][dt][r] * inv[r];
      }
    }
  }
}

// ---------------------------------------------------------------------------
extern "C" void kernel_launch(void* const* d_in, const int* in_sizes, int n_in,
                              void* d_out, int out_size, void* d_ws,
                              size_t ws_size, hipStream_t stream) {
  (void)in_sizes; (void)n_in; (void)out_size; (void)ws_size;
  const float* hidden = (const float*)d_in[0];
  const float* mask   = (const float*)d_in[1];
  const float* Wq     = (const float*)d_in[2];
  const float* bq     = (const float*)d_in[3];
  const float* Wk     = (const float*)d_in[4];
  const float* bk     = (const float*)d_in[5];
  const float* Wv     = (const float*)d_in[6];
  const float* bv     = (const float*)d_in[7];
  float* out = (float*)d_out;

  uint8_t* w = (uint8_t*)d_ws;
  f16* Wt   = (f16*)(w);                               //  6 MB
  f16* X16  = (f16*)(w + (size_t)6 * 1024 * 1024);     // 16 MB
  f16* Q16  = (f16*)(w + (size_t)22 * 1024 * 1024);    // 16 MB (pre-scaled)
  f16* K16  = (f16*)(w + (size_t)38 * 1024 * 1024);    // 16 MB
  f16* Vt16 = (f16*)(w + (size_t)54 * 1024 * 1024);    // 16 MB, transposed

  cast_w_kernel<<<dim3(16, 16, 3), 256, 0, stream>>>(Wq, Wk, Wv, Wt);
  cast_x_kernel<<<4096, 256, 0, stream>>>(hidden, X16);
  qkv_gemm_kernel<<<dim3(8, 64, 3), 256, 0, stream>>>(X16, Wt, bq, bk, bv,
                                                      Q16, K16, Vt16);
  flash_kernel<<<dim3(16, 64), 256, 0, stream>>>(Q16, K16, Vt16, mask, out);
}

// Round 2
// 257.262 us; speedup vs baseline: 1.1032x; 1.1032x over previous
//
#include <hip/hip_runtime.h>
#include <hip/hip_bf16.h>
#include <cstdint>

typedef _Float16 f16;
typedef f16 f16x8 __attribute__((ext_vector_type(8)));
typedef f16 f16x4 __attribute__((ext_vector_type(4)));
typedef float f32x4 __attribute__((ext_vector_type(4)));

#define MFMA16(a, b, c) __builtin_amdgcn_mfma_f32_16x16x32_f16((a), (b), (c), 0, 0, 0)

constexpr int Bc = 4, Sc = 2048, Dc = 1024, Hc = 16, DHc = 64;

typedef __attribute__((address_space(1))) const uint32_t gbl_u32;
typedef __attribute__((address_space(3))) uint32_t lds_u32;
__device__ __forceinline__ void gld_lds16(const void* g, void* l) {
  __builtin_amdgcn_global_load_lds((gbl_u32*)g, (lds_u32*)l, 16, 0, 0);
}

// ---------------------------------------------------------------------------
// Kernel 1: cast+transpose weights: W fp32 [K=1024][N=1024] -> Wt f16 [z][N][K]
// (viewed by the GEMM as one [3072][1024] B^T matrix)
// ---------------------------------------------------------------------------
__global__ __launch_bounds__(256) void cast_w_kernel(
    const float* __restrict__ Wq, const float* __restrict__ Wk,
    const float* __restrict__ Wv, f16* __restrict__ Wt) {
  __shared__ __align__(16) f16 T[64][66];
  const int z = blockIdx.z;
  const float* W = (z == 0) ? Wq : (z == 1) ? Wk : Wv;
  const int n0 = blockIdx.x * 64, k0 = blockIdx.y * 64;
  const int t = threadIdx.x;
#pragma unroll
  for (int p = 0; p < 4; p++) {
    int idx = t + p * 256;
    int r = idx >> 4, c = idx & 15;
    float4 v = *(const float4*)(W + (size_t)(k0 + r) * Dc + n0 + c * 4);
    T[r][c * 4 + 0] = (f16)v.x;
    T[r][c * 4 + 1] = (f16)v.y;
    T[r][c * 4 + 2] = (f16)v.z;
    T[r][c * 4 + 3] = (f16)v.w;
  }
  __syncthreads();
#pragma unroll
  for (int p = 0; p < 2; p++) {
    int idx = t + p * 256;
    int n = idx >> 3, c = idx & 7;
    f16x8 tmp;
#pragma unroll
    for (int j = 0; j < 8; j++) tmp[j] = T[c * 8 + j][n];
    *(f16x8*)(Wt + ((size_t)z * Dc + n0 + n) * Dc + k0 + c * 8) = tmp;
  }
}

// ---------------------------------------------------------------------------
// Kernel 1b: cast X fp32 -> f16.
// ---------------------------------------------------------------------------
__global__ __launch_bounds__(256) void cast_x_kernel(const float* __restrict__ X,
                                                     f16* __restrict__ X16) {
  size_t i = ((size_t)blockIdx.x * 256 + threadIdx.x) * 8;
  float4 a = *(const float4*)(X + i);
  float4 b = *(const float4*)(X + i + 4);
  f16x8 h;
  h[0] = (f16)a.x; h[1] = (f16)a.y; h[2] = (f16)a.z; h[3] = (f16)a.w;
  h[4] = (f16)b.x; h[5] = (f16)b.y; h[6] = (f16)b.z; h[7] = (f16)b.w;
  *(f16x8*)(X16 + i) = h;
}

// ---------------------------------------------------------------------------
// Kernel 2: fused QKV GEMM (N=3072), m97-style, XCD-chunked block swizzle.
// Rationale (R2): staging traffic was 1536 blocks x 512 KB = 786 MB with
// consecutive blocks scattered round-robin over 8 XCDs -> per-XCD L2
// working set ~100 MB -> everything missed to L3. Swizzle: XCD x owns
// m-tiles [8x,8x+8) for ALL 24 n-tiles, m fastest -> per-XCD working set
// = 8 X-tiles (2 MB, L2-resident) + one W-tile at a time (256 KB).
// Aggregate fetch ~786 MB -> ~65 MB.
// Q output is pre-scaled by 1/8 * log2(e) for the flash exp2 path.
// grid: 1536 linear blocks; lin&7 = XCD (round-robin dispatch assumption,
// performance-only).
// ---------------------------------------------------------------------------
__global__ __launch_bounds__(256) void qkv_gemm_kernel(
    const f16* __restrict__ X16, const f16* __restrict__ Wt,
    const float* __restrict__ bq, const float* __restrict__ bk,
    const float* __restrict__ bv, f16* __restrict__ Qo, f16* __restrict__ Ko,
    f16* __restrict__ Vo) {
  const int lin = blockIdx.x;
  const int xcd = lin & 7, jj = lin >> 3;   // jj in [0,192)
  const int bn = jj >> 3;                   // 0..23 (n-tile over fused N=3072)
  const int bm = (xcd << 3) | (jj & 7);     // 0..63 (m-tile; inner index)
  const int z = bn >> 3;
  const int n0 = (bn & 7) * 128;            // col base within this z
  const int m0 = bm * 128;
  const f16* W = Wt + (size_t)bn * 128 * Dc;  // rows [bn*128, bn*128+128)
  const float* bias = (z == 0) ? bq : (z == 1) ? bk : bv;

  __shared__ __align__(16) f16 Xs[128 * 32];
  __shared__ __align__(16) f16 Ws[128 * 32];

  const int t = threadIdx.x;
  const int wave = t >> 6, lane = t & 63;
  const int l16 = lane & 15, quad = lane >> 4;
  const int wm = (wave >> 1) * 64, wn = (wave & 1) * 64;

  f32x4 acc[4][4];
#pragma unroll
  for (int i = 0; i < 4; i++)
#pragma unroll
    for (int j = 0; j < 4; j++) acc[i][j] = (f32x4){0.f, 0.f, 0.f, 0.f};

  for (int k0 = 0; k0 < Dc; k0 += 32) {
#pragma unroll
    for (int p = 0; p < 2; p++) {
      int cb = p * 256 + wave * 64;
      int chunk = cb + lane;
      int row = chunk >> 2, c8 = (chunk & 3) * 8;
      gld_lds16(X16 + (size_t)(m0 + row) * Dc + k0 + c8, (f16*)Xs + (size_t)cb * 8);
      gld_lds16(W + (size_t)row * Dc + k0 + c8, (f16*)Ws + (size_t)cb * 8);
    }
    __syncthreads();

    f16x8 aF[4], bF[4];
#pragma unroll
    for (int mt = 0; mt < 4; mt++)
      aF[mt] = *(const f16x8*)(&Xs[(wm + mt * 16 + l16) * 32 + quad * 8]);
#pragma unroll
    for (int nt = 0; nt < 4; nt++)
      bF[nt] = *(const f16x8*)(&Ws[(wn + nt * 16 + l16) * 32 + quad * 8]);
#pragma unroll
    for (int mt = 0; mt < 4; mt++)
#pragma unroll
      for (int nt = 0; nt < 4; nt++)
        acc[mt][nt] = MFMA16(aF[mt], bF[nt], acc[mt][nt]);
    __syncthreads();
  }

#pragma unroll
  for (int nt = 0; nt < 4; nt++) {
    int col = n0 + wn + nt * 16 + l16;   // within-z column, 0..1023
    float bval = bias[col];
    int h = col >> 6, d = col & 63;
    if (z == 2) {
#pragma unroll
      for (int mt = 0; mt < 4; mt++) {
        int m = m0 + wm + mt * 16 + quad * 4;
        int b = m >> 11, sbase = m & 2047;
        f16x4 pk;
#pragma unroll
        for (int r = 0; r < 4; r++) pk[r] = (f16)(acc[mt][nt][r] + bval);
        *(f16x4*)(Vo + (((size_t)(b * Hc + h)) * DHc + d) * Sc + sbase) = pk;
      }
    } else {
      // z==0 (Q): fold softmax scale 1/sqrt(64)=0.125 AND log2(e) so flash
      // uses exp2 directly.  z==1 (K): 1.0.
      const float sc = (z == 0) ? 0.18033688011112042f : 1.0f;
      f16* O = (z == 0) ? Qo : Ko;
#pragma unroll
      for (int mt = 0; mt < 4; mt++) {
#pragma unroll
        for (int r = 0; r < 4; r++) {
          int m = m0 + wm + mt * 16 + quad * 4 + r;
          int b = m >> 11, s = m & 2047;
          O[(((size_t)(b * Hc + h)) * Sc + s) * DHc + d] =
              (f16)((acc[mt][nt][r] + bval) * sc);
        }
      }
    }
  }
}

// ---------------------------------------------------------------------------
// Kernel 3: flash attention — register-resident P via KEY-PERMUTED K staging.
//
// R2 changes (flash was memory-bound: FETCH 139 MB @1.46 TB/s ~ 95 us of
// the 119; VALU cut in R1 changed nothing):
//  - XCD-chunked swizzle: XCD x owns bh in [8x,8x+8) -> per-XCD K/V working
//    set 8 x 512 KB = 4 MB (L2-resident, reused by 16 qtile-blocks) instead
//    of 32 MB. Expect FETCH 139 -> ~60-75 MB.
//  - mask moved to LDS at prologue, pre-scaled by log2(e): removes 4 vmem
//    loads + 16 muls per chunk; staging is now the only vmem in the loop.
// ---------------------------------------------------------------------------
__global__ __launch_bounds__(256) void flash_kernel(
    const f16* __restrict__ Q, const f16* __restrict__ K,
    const f16* __restrict__ Vt, const float* __restrict__ mask,
    float* __restrict__ out) {
  const int lin = blockIdx.x;               // 1024 blocks
  const int xcd = lin & 7, jj = lin >> 3;   // jj in [0,128)
  const int bh = (xcd << 3) | (jj & 7);     // 0..63 (inner: bh cycles fastest)
  const int qt = jj >> 3;                   // 0..15
  const int b = bh >> 4, h = bh & 15;
  const int t = threadIdx.x;
  const int wave = t >> 6, lane = t & 63;
  const int l16 = lane & 15, quad = lane >> 4;
  const int qbase = qt * 128 + wave * 32;

  __shared__ __align__(16) f16 Ks[2][4096];  // [buf][half*2048+row*32+oct*8]
  __shared__ __align__(16) f16 Vs[2][4096];  // [buf][kh*2048+dh*32+oct*8]
  __shared__ __align__(16) float Ms[2048];   // mask row * log2(e)

  const f16* Kb = K + (size_t)bh * Sc * DHc;
  const f16* Vb = Vt + (size_t)bh * DHc * Sc;

  constexpr float L2E = 1.44269504088896340736f;

  // swizzled b128 read position (same for K and V frags)
  const int qsw8 = (quad ^ ((l16 >> 1) & 3)) * 8;

  // ---- hoisted staging state: per-lane global ptrs + wave-uniform LDS offs.
  // octet i -> half=i>>8, row=(i>>2)&63, pos q8=i&3 holds global octet
  // q8^((row>>1)&3). K rows are PERMUTED: staged row k holds global key
  // phys(k): [n1 n0 q1 q0 r1 r0] -> [n1 q1 q0 n0 r1 r0].
  const f16* kp[2];
  const f16* vp[2];
  int ldsOff[2];
#pragma unroll
  for (int p = 0; p < 2; p++) {
    int cb = p * 256 + wave * 64;  // wave-uniform octet base
    int i = cb + lane;
    int half = i >> 8, row = (i >> 2) & 63, q8 = i & 3;
    int q8g = q8 ^ ((row >> 1) & 3);
    int g = (row & 32) | ((row & 12) << 1) | ((row & 16) >> 2) | (row & 3);
    kp[p] = Kb + (size_t)g * DHc + half * 32 + q8g * 8;
    vp[p] = Vb + (size_t)row * Sc + half * 32 + q8g * 8;
    ldsOff[p] = cb * 8;
  }
  auto stage = [&](int buf) {
#pragma unroll
    for (int p = 0; p < 2; p++) {
      gld_lds16(kp[p], (f16*)Ks + buf * 4096 + ldsOff[p]);
      gld_lds16(vp[p], (f16*)Vs + buf * 4096 + ldsOff[p]);
      kp[p] += 64 * DHc;  // next chunk: 64 more key rows
      vp[p] += 64;        // next chunk: 64 more key columns
    }
  };

  // Q B-frags for 2 m-tiles (B[k=quad*8+j -> dh][n=l16 -> query]); pre-scaled
  // by 0.125*log2(e) in the GEMM epilogue.
  f16x8 qa[2][2];
#pragma unroll
  for (int mt = 0; mt < 2; mt++) {
    const f16* qb = Q + ((size_t)bh * Sc + qbase + mt * 16 + l16) * DHc;
    qa[mt][0] = *(const f16x8*)(qb + quad * 8);
    qa[mt][1] = *(const f16x8*)(qb + 32 + quad * 8);
  }

  // all-ones B-frag for the l row-sum MFMAs
  f16x8 ones;
#pragma unroll
  for (int j = 0; j < 8; j++) ones[j] = (f16)1.0f;

  // prologue: stage chunk 0; fill mask LDS (pre-scaled into exp2 domain)
  stage(0);
  {
    const float* mrow = mask + (size_t)b * Sc + t * 8;
    float4 a0 = *(const float4*)(mrow);
    float4 a1 = *(const float4*)(mrow + 4);
    f32x4 m0 = (f32x4){a0.x * L2E, a0.y * L2E, a0.z * L2E, a0.w * L2E};
    f32x4 m1 = (f32x4){a1.x * L2E, a1.y * L2E, a1.z * L2E, a1.w * L2E};
    *(f32x4*)(&Ms[t * 8]) = m0;
    *(f32x4*)(&Ms[t * 8 + 4]) = m1;
  }
  __syncthreads();

  f32x4 lacc[2];
  f32x4 o[2][4];
#pragma unroll
  for (int mt = 0; mt < 2; mt++) {
    lacc[mt] = (f32x4){0.f, 0.f, 0.f, 0.f};
#pragma unroll
    for (int dt = 0; dt < 4; dt++) o[mt][dt] = (f32x4){0.f, 0.f, 0.f, 0.f};
  }

  for (int c = 0; c < 32; c++) {
    const int buf = c & 1;
    // staging for c+1 first: only vmem in the loop; stays in flight until
    // the compiler's pre-barrier drain at the end of this chunk.
    if (c < 31) stage(buf ^ 1);

    // mask C-init from LDS (broadcast within quads, conflict-free across)
    const int mb = c * 64 + quad * 8;
    f32x4 minit[4];
    minit[0] = *(const f32x4*)(&Ms[mb + 0]);
    minit[1] = *(const f32x4*)(&Ms[mb + 4]);
    minit[2] = *(const f32x4*)(&Ms[mb + 32]);
    minit[3] = *(const f32x4*)(&Ms[mb + 36]);

    // K A-frags (staged/permuted rows), swizzled b128 positions
    f16x8 ka[4][2];
#pragma unroll
    for (int nt = 0; nt < 4; nt++) {
      int rb = (nt * 16 + l16) * 32 + qsw8;
      ka[nt][0] = *(const f16x8*)(&Ks[buf][rb]);
      ka[nt][1] = *(const f16x8*)(&Ks[buf][2048 + rb]);
    }

    // ---- QK both m-tiles: S^T = K*Q^T + mask (C-init), log2 domain ----
    f32x4 s0[4], s1[4];
#pragma unroll
    for (int nt = 0; nt < 4; nt++) {
      f32x4 a = minit[nt];
      a = MFMA16(ka[nt][0], qa[0][0], a);
      a = MFMA16(ka[nt][1], qa[0][1], a);
      s0[nt] = a;
      f32x4 a2 = minit[nt];
      a2 = MFMA16(ka[nt][0], qa[1][0], a2);
      a2 = MFMA16(ka[nt][1], qa[1][1], a2);
      s1[nt] = a2;
    }

    // ---- exp2 + pack: s[2blk+(j>=4)][j&3] -> A-frag element j of block blk.
    // Under the key permutation this IS the 16x16x32 A-layout. ----
    f16x8 pa[2][2];  // [mt][blk]
#pragma unroll
    for (int blk = 0; blk < 2; blk++) {
      f16x8 p0, p1;
#pragma unroll
      for (int half = 0; half < 2; half++) {
        int nt = blk * 2 + half;
#pragma unroll
        for (int r = 0; r < 4; r++) {
          p0[half * 4 + r] = (f16)__builtin_amdgcn_exp2f(s0[nt][r]);
          p1[half * 4 + r] = (f16)__builtin_amdgcn_exp2f(s1[nt][r]);
        }
      }
      pa[0][blk] = p0;
      pa[1][blk] = p1;
    }

    // ---- l row-sums on the MFMA pipe: D[q][*] = sum_k P[q][k] ----
    lacc[0] = MFMA16(pa[0][0], ones, lacc[0]);
    lacc[0] = MFMA16(pa[0][1], ones, lacc[0]);
    lacc[1] = MFMA16(pa[1][0], ones, lacc[1]);
    lacc[1] = MFMA16(pa[1][1], ones, lacc[1]);

    // ---- PV: 16x16x32, V b128 frags shared by both m-tiles (0-conflict) ----
#pragma unroll
    for (int dt = 0; dt < 4; dt++) {
      int rb = (dt * 16 + l16) * 32 + qsw8;
      f16x8 v0 = *(const f16x8*)(&Vs[buf][rb]);
      f16x8 v1 = *(const f16x8*)(&Vs[buf][2048 + rb]);
      o[0][dt] = MFMA16(pa[0][0], v0, o[0][dt]);
      o[0][dt] = MFMA16(pa[0][1], v1, o[0][dt]);
      o[1][dt] = MFMA16(pa[1][0], v0, o[1][dt]);
      o[1][dt] = MFMA16(pa[1][1], v1, o[1][dt]);
    }

    // one barrier per chunk: all waves done with buf; staging of c+1 drains.
    __syncthreads();
  }

  // ---- epilogue: lacc D-layout rows (quad*4+r) == o rows; no shuffles ----
#pragma unroll
  for (int mt = 0; mt < 2; mt++) {
    float inv[4];
#pragma unroll
    for (int r = 0; r < 4; r++) inv[r] = 1.0f / lacc[mt][r];
#pragma unroll
    for (int dt = 0; dt < 4; dt++) {
      int col = h * 64 + dt * 16 + l16;
#pragma unroll
      for (int r = 0; r < 4; r++) {
        int row = qbase + mt * 16 + quad * 4 + r;
        out[((size_t)b * Sc + row) * Dc + col] = o[mt][dt][r] * inv[r];
      }
    }
  }
}

// ---------------------------------------------------------------------------
extern "C" void kernel_launch(void* const* d_in, const int* in_sizes, int n_in,
                              void* d_out, int out_size, void* d_ws,
                              size_t ws_size, hipStream_t stream) {
  (void)in_sizes; (void)n_in; (void)out_size; (void)ws_size;
  const float* hidden = (const float*)d_in[0];
  const float* mask   = (const float*)d_in[1];
  const float* Wq     = (const float*)d_in[2];
  const float* bq     = (const float*)d_in[3];
  const float* Wk     = (const float*)d_in[4];
  const float* bk     = (const float*)d_in[5];
  const float* Wv     = (const float*)d_in[6];
  const float* bv     = (const float*)d_in[7];
  float* out = (float*)d_out;

  uint8_t* w = (uint8_t*)d_ws;
  f16* Wt   = (f16*)(w);                               //  6 MB
  f16* X16  = (f16*)(w + (size_t)6 * 1024 * 1024);     // 16 MB
  f16* Q16  = (f16*)(w + (size_t)22 * 1024 * 1024);    // 16 MB (pre-scaled)
  f16* K16  = (f16*)(w + (size_t)38 * 1024 * 1024);    // 16 MB
  f16* Vt16 = (f16*)(w + (size_t)54 * 1024 * 1024);    // 16 MB, transposed

  cast_w_kernel<<<dim3(16, 16, 3), 256, 0, stream>>>(Wq, Wk, Wv, Wt);
  cast_x_kernel<<<4096, 256, 0, stream>>>(hidden, X16);
  qkv_gemm_kernel<<<dim3(1536), 256, 0, stream>>>(X16, Wt, bq, bk, bv,
                                                  Q16, K16, Vt16);
  flash_kernel<<<dim3(1024), 256, 0, stream>>>(Q16, K16, Vt16, mask, out);
}